// Round 2
// baseline (640.875 us; speedup 1.0000x reference)
//
#include <hip/hip_runtime.h>

// DrugInteractionAttention — S=1 attention collapses; everything folds into one
// bf16 MFMA GEMM [16384 x 2048] @ [2048 x 2048] with sigmoid-gate epilogue,
// plus a tiny logits pass. Weight folding (6x 1024^3 GEMMs) done per-call.
//
// ws layout (bytes), total ~100.7 MB:
//   Abf   [16384][2048] bf16 : 0
//   WT    [2048][2048]  bf16 : 67108864   (packed, transposed folded weight)
//   Wvbf  [4][1024][1024]    : 75497472
//   WoT   [4][1024][1024]    : 83886080   (transposed bf16 Wo)
//   WgT   [1024][2048]       : 92274688   (transposed bf16 Wg)
//   Mbuf  [2][1024][1024]    : 96468992   (M2' = Wv2@Wo2, M3' = Wv3@Wo3)
//   t4    [4][1024] f32      : 100663296  (bv[g]@Wo[g]+bo[g])
//   cLin  [1024] f32         : 100679680
//   cG    [1024] f32         : 100683776
//   cC    [3]   f32          : 100687872
//   Lw    [2048][3] f32      : 100688128

typedef unsigned short ushort_t;
typedef __attribute__((ext_vector_type(4))) float f32x4;
typedef __attribute__((ext_vector_type(8))) __bf16 bf16x8;

__device__ __forceinline__ unsigned short f2bf(float f) {
    unsigned int u = __float_as_uint(f);
    u = (u + 0x7fffu + ((u >> 16) & 1u)) >> 16;   // RNE
    return (unsigned short)u;
}
__device__ __forceinline__ float bf2f(unsigned int u) {
    return __uint_as_float(u << 16);
}

// async global->LDS, 16B per lane; LDS dest is wave-uniform base (+lane*16 by HW).
__device__ __forceinline__ void gload16(const void* g, void* l) {
    __builtin_amdgcn_global_load_lds(
        (const __attribute__((address_space(1))) void*)g,
        (__attribute__((address_space(3))) void*)l, 16, 0, 0);
}

__device__ __forceinline__ f32x4 mfma16(bf16x8 a, bf16x8 b, f32x4 c) {
    return __builtin_amdgcn_mfma_f32_16x16x32_bf16(a, b, c, 0, 0, 0);
}

// ---- conversion kernels -----------------------------------------------------

// Abf[i][k] = bf16( k<1024 ? a[i][k] : b[i][k-1024] ), 8 elems/thread
__global__ __launch_bounds__(256) void convA_kernel(
    const float* __restrict__ a, const float* __restrict__ b,
    ushort_t* __restrict__ Abf) {
    int idx = blockIdx.x * 256 + threadIdx.x;          // 4,194,304 threads
    size_t e0 = (size_t)idx * 8;
    int i = (int)(e0 >> 11);
    int k = (int)(e0 & 2047);
    const float* src = (k < 1024) ? (a + (size_t)i * 1024 + k)
                                  : (b + (size_t)i * 1024 + (k - 1024));
    float4 f0 = ((const float4*)src)[0];
    float4 f1 = ((const float4*)src)[1];
    uint4 o;
    o.x = (unsigned)f2bf(f0.x) | ((unsigned)f2bf(f0.y) << 16);
    o.y = (unsigned)f2bf(f0.z) | ((unsigned)f2bf(f0.w) << 16);
    o.z = (unsigned)f2bf(f1.x) | ((unsigned)f2bf(f1.y) << 16);
    o.w = (unsigned)f2bf(f1.z) | ((unsigned)f2bf(f1.w) << 16);
    *(uint4*)(Abf + e0) = o;
}

// straight f32 -> bf16 copy (Wv, 4M elems)
__global__ __launch_bounds__(256) void convC_kernel(
    const float* __restrict__ src, ushort_t* __restrict__ dst) {
    size_t e0 = ((size_t)blockIdx.x * 256 + threadIdx.x) * 8;
    float4 f0 = ((const float4*)(src + e0))[0];
    float4 f1 = ((const float4*)(src + e0))[1];
    uint4 o;
    o.x = (unsigned)f2bf(f0.x) | ((unsigned)f2bf(f0.y) << 16);
    o.y = (unsigned)f2bf(f0.z) | ((unsigned)f2bf(f0.w) << 16);
    o.z = (unsigned)f2bf(f1.x) | ((unsigned)f2bf(f1.y) << 16);
    o.w = (unsigned)f2bf(f1.z) | ((unsigned)f2bf(f1.w) << 16);
    *(uint4*)(dst + e0) = o;
}

// transpose f32 [R][C] -> bf16 [C][R], 32x32 tiles, z-batched
__global__ __launch_bounds__(256) void convT_kernel(
    const float* __restrict__ src, ushort_t* __restrict__ dst,
    int R, int C, long zs, long zd) {
    __shared__ float tile[32][33];
    int tx = threadIdx.x & 31, ty = threadIdx.x >> 5;  // ty 0..7
    const float* s = src + (size_t)blockIdx.z * zs;
    ushort_t* d = dst + (size_t)blockIdx.z * zd;
    int r0 = blockIdx.y * 32, c0 = blockIdx.x * 32;
#pragma unroll
    for (int p = 0; p < 4; ++p)
        tile[p * 8 + ty][tx] = s[(size_t)(r0 + p * 8 + ty) * C + c0 + tx];
    __syncthreads();
#pragma unroll
    for (int p = 0; p < 4; ++p)
        d[(size_t)(c0 + p * 8 + ty) * R + r0 + tx] = f2bf(tile[tx][p * 8 + ty]);
}

// ---- bias chains ------------------------------------------------------------

// t4[g][j] = bv[g] @ Wo[g] + bo[g]
__global__ __launch_bounds__(256) void biasT_kernel(
    const float* __restrict__ bv, const float* __restrict__ Wo,
    const float* __restrict__ bo, float* __restrict__ t4) {
    int g = blockIdx.x >> 2;
    int j = (blockIdx.x & 3) * 256 + threadIdx.x;
    const float* W = Wo + (size_t)g * 1048576;
    const float* v = bv + g * 1024;
    float acc = 0.f;
    for (int k = 0; k < 1024; ++k) acc += v[k] * W[(size_t)k * 1024 + j];
    t4[g * 1024 + j] = acc + bo[g * 1024 + j];
}

// cG[j] = t2@Wg_top + t3@Wg_bot + bg;  cLin[j] = t0[j] + t1[j]
__global__ __launch_bounds__(256) void cgc_kernel(
    const float* __restrict__ t4, const float* __restrict__ Wg,
    const float* __restrict__ bg, float* __restrict__ cLin,
    float* __restrict__ cG) {
    int j = blockIdx.x * 256 + threadIdx.x;
    float acc = bg[j];
    for (int k = 0; k < 1024; ++k) acc += t4[2048 + k] * Wg[(size_t)k * 1024 + j];
    for (int k = 0; k < 1024; ++k) acc += t4[3072 + k] * Wg[(size_t)(1024 + k) * 1024 + j];
    cG[j] = acc;
    cLin[j] = t4[j] + t4[1024 + j];
}

// cC[t] = t2@Wc_top + t3@Wc_bot + bc
__global__ __launch_bounds__(256) void ccc_kernel(
    const float* __restrict__ t4, const float* __restrict__ Wc,
    const float* __restrict__ bc, float* __restrict__ cC) {
    __shared__ float red[192];
    int tid = threadIdx.x;
    if (tid < 192) {
        int t = tid % 3, c = tid / 3;   // c 0..63
        float acc = 0.f;
        for (int kk = 0; kk < 32; ++kk) {
            int k = c * 32 + kk;
            float s = (k < 1024) ? t4[2048 + k] : t4[3072 + (k - 1024)];
            acc += s * Wc[(size_t)k * 3 + t];
        }
        red[tid] = acc;
    }
    __syncthreads();
    if (tid < 3) {
        float s = bc[tid];
        for (int c = 0; c < 64; ++c) s += red[tid + 3 * c];
        cC[tid] = s;
    }
}

// Lw[k][t]: rows 0..1023 = M3'@Wc_bot (drug_a), rows 1024..2047 = M2'@Wc_top
__global__ __launch_bounds__(256) void lfold_kernel(
    const ushort_t* __restrict__ Mbuf, const float* __restrict__ Wc,
    float* __restrict__ Lw) {
    int gid = blockIdx.x * 256 + threadIdx.x;  // 6144
    int half = gid / 3072;
    int idx = gid % 3072;
    int k = idx / 3, t = idx % 3;
    const ushort_t* Mrow = Mbuf + (half == 0 ? 1048576 : 0) + (size_t)k * 1024;
    const float* Wcp = Wc + (half == 0 ? 3072 : 0);
    float acc = 0.f;
    for (int m = 0; m < 1024; m += 2) {
        unsigned int x = *(const unsigned int*)(Mrow + m);
        acc += bf2f(x & 0xffffu) * Wcp[(size_t)m * 3 + t] +
               bf2f(x >> 16) * Wcp[(size_t)(m + 1) * 3 + t];
    }
    Lw[(size_t)(half * 1024 + k) * 3 + t] = acc;
}

// ---- fold GEMM body (NT, 64x64x64 tiles, 2 waves, K=1024) -------------------
// C[m][n] = sum_q A[m][q] * BT[n][q], output bf16 with row remap:
//   rowMode 0: orow=m   1: (m>>6)*128+(m&63)   2: (m>>6)*128+64+(m&63)
__device__ __forceinline__ void fold_body(
    ushort_t* sA, ushort_t* sB,
    const ushort_t* __restrict__ A, int lda,
    const ushort_t* __restrict__ BT, int ldbt,
    ushort_t* __restrict__ ob, int ldout, int rowMode, int colOff,
    int bx, int by) {
    int tid = threadIdx.x, w = tid >> 6, l = tid & 63;
    f32x4 acc[2][4];
#pragma unroll
    for (int i = 0; i < 2; ++i)
#pragma unroll
        for (int j = 0; j < 4; ++j) acc[i][j] = (f32x4){0.f, 0.f, 0.f, 0.f};
    int srow = l >> 3, skoff = (l & 7) * 8;
    const ushort_t* Abase = A + (size_t)(by * 64 + w * 32 + srow) * lda + skoff;
    const ushort_t* Bbase = BT + (size_t)(bx * 64 + w * 32 + srow) * ldbt + skoff;
    for (int k0 = 0; k0 < 1024; k0 += 64) {
        __syncthreads();
#pragma unroll
        for (int i = 0; i < 4; ++i) {
            gload16(Abase + (size_t)i * 8 * lda + k0, &sA[(w * 32 + i * 8) * 64]);
            gload16(Bbase + (size_t)i * 8 * ldbt + k0, &sB[(w * 32 + i * 8) * 64]);
        }
        __syncthreads();
#pragma unroll
        for (int kk = 0; kk < 2; ++kk) {
            int kb = kk * 32 + (l >> 4) * 8;
            bf16x8 aF[2], bF[4];
#pragma unroll
            for (int mi = 0; mi < 2; ++mi)
                aF[mi] = *(const bf16x8*)&sA[(w * 32 + mi * 16 + (l & 15)) * 64 + kb];
#pragma unroll
            for (int ni = 0; ni < 4; ++ni)
                bF[ni] = *(const bf16x8*)&sB[(ni * 16 + (l & 15)) * 64 + kb];
#pragma unroll
            for (int mi = 0; mi < 2; ++mi)
#pragma unroll
                for (int ni = 0; ni < 4; ++ni)
                    acc[mi][ni] = mfma16(aF[mi], bF[ni], acc[mi][ni]);
        }
    }
    int col16 = l & 15, rg = (l >> 4) * 4;
#pragma unroll
    for (int mi = 0; mi < 2; ++mi)
#pragma unroll
        for (int ni = 0; ni < 4; ++ni) {
            int n = bx * 64 + ni * 16 + col16;
#pragma unroll
            for (int r = 0; r < 4; ++r) {
                int m = by * 64 + w * 32 + mi * 16 + rg + r;
                int orow = (rowMode == 0)
                               ? m
                               : ((m >> 6) * 128 + (rowMode == 2 ? 64 : 0) + (m & 63));
                ob[(size_t)orow * ldout + colOff + n] = f2bf(acc[mi][ni][r]);
            }
        }
}

// merged L1+L2: z=0,1 -> WT lin rows (M'^T, rowMode1); z=2,3 -> Mbuf (M', rowMode0)
__global__ __launch_bounds__(128) void fold_l12(
    const ushort_t* __restrict__ Wvbf, const ushort_t* __restrict__ WoT,
    ushort_t* __restrict__ WT, ushort_t* __restrict__ Mbuf) {
    __shared__ alignas(16) ushort_t sA[64 * 64];
    __shared__ alignas(16) ushort_t sB[64 * 64];
    int z = blockIdx.z;
    const ushort_t *A, *BT;
    ushort_t* ob;
    int rowMode, colOff, ldout;
    if (z < 2) {   // C = M_z'^T -> WT lin, cols z*1024..
        A = WoT + (size_t)z * 1048576;
        BT = Wvbf + (size_t)z * 1048576;
        ob = WT; rowMode = 1; colOff = z * 1024; ldout = 2048;
    } else {       // C = M_z' -> Mbuf[z-2]
        A = Wvbf + (size_t)z * 1048576;
        BT = WoT + (size_t)z * 1048576;
        ob = Mbuf + (size_t)(z - 2) * 1048576; rowMode = 0; colOff = 0; ldout = 1024;
    }
    fold_body(sA, sB, A, 1024, BT, 1024, ob, ldout, rowMode, colOff,
              blockIdx.x, blockIdx.y);
}

// L34: z=0 gate-a = NT(WgT[:,1024:], M3') -> WT gate cols 0..1023 (rowMode2)
//      z=1 gate-b = NT(WgT[:,0:1024], M2') -> WT gate cols 1024..2047
__global__ __launch_bounds__(128) void fold_l34(
    const ushort_t* __restrict__ WgT, const ushort_t* __restrict__ Mbuf,
    ushort_t* __restrict__ WT) {
    __shared__ alignas(16) ushort_t sA[64 * 64];
    __shared__ alignas(16) ushort_t sB[64 * 64];
    int z = blockIdx.z;
    const ushort_t* A = WgT + (z == 0 ? 1024 : 0);
    const ushort_t* BT = Mbuf + (z == 0 ? 1048576 : 0);
    fold_body(sA, sB, A, 2048, BT, 1024, WT, 2048, 2, z * 1024,
              blockIdx.x, blockIdx.y);
}

// ---- main fused GEMM (128x128x64, 4 waves) ----------------------------------
// A [16384][2048] bf16, WT [2048][2048] bf16 packed: tile nt's 128 rows are
// 64 lin cols then 64 gate cols (j = nt*64+c). Each wave computes 32 rows x
// all 64 j, lin+gate accs in-register, epilogue fuses sigmoid gate.
__global__ __launch_bounds__(256) void main_mm(
    const ushort_t* __restrict__ A, const ushort_t* __restrict__ WT,
    const float* __restrict__ cLin, const float* __restrict__ cG,
    float* __restrict__ out) {
    __shared__ alignas(16) ushort_t sA[128 * 64];
    __shared__ alignas(16) ushort_t sB[128 * 64];
    int tid = threadIdx.x, w = tid >> 6, l = tid & 63;
    int bid = blockIdx.x;
    int swz = ((bid & 7) << 8) | (bid >> 3);   // 2048 wgs, 8 XCDs, bijective
    int mt = swz >> 4, nt = swz & 15;
    size_t m0 = (size_t)mt * 128;
    f32x4 accL[2][4], accG[2][4];
#pragma unroll
    for (int i = 0; i < 2; ++i)
#pragma unroll
        for (int j = 0; j < 4; ++j) {
            accL[i][j] = (f32x4){0.f, 0.f, 0.f, 0.f};
            accG[i][j] = (f32x4){0.f, 0.f, 0.f, 0.f};
        }
    int srow = l >> 3, skoff = (l & 7) * 8;
    const ushort_t* Abase = A + (m0 + w * 32 + srow) * 2048 + skoff;
    const ushort_t* Bbase = WT + ((size_t)nt * 128 + w * 32 + srow) * 2048 + skoff;
    for (int k0 = 0; k0 < 2048; k0 += 64) {
        __syncthreads();
#pragma unroll
        for (int i = 0; i < 4; ++i) {
            gload16(Abase + (size_t)i * 8 * 2048 + k0, &sA[(w * 32 + i * 8) * 64]);
            gload16(Bbase + (size_t)i * 8 * 2048 + k0, &sB[(w * 32 + i * 8) * 64]);
        }
        __syncthreads();
#pragma unroll
        for (int kk = 0; kk < 2; ++kk) {
            int kb = kk * 32 + (l >> 4) * 8;
            bf16x8 aF[2], bF[8];
#pragma unroll
            for (int mi = 0; mi < 2; ++mi)
                aF[mi] = *(const bf16x8*)&sA[(w * 32 + mi * 16 + (l & 15)) * 64 + kb];
#pragma unroll
            for (int ni = 0; ni < 8; ++ni)
                bF[ni] = *(const bf16x8*)&sB[(ni * 16 + (l & 15)) * 64 + kb];
#pragma unroll
            for (int mi = 0; mi < 2; ++mi)
#pragma unroll
                for (int ni = 0; ni < 4; ++ni) {
                    accL[mi][ni] = mfma16(aF[mi], bF[ni], accL[mi][ni]);
                    accG[mi][ni] = mfma16(aF[mi], bF[4 + ni], accG[mi][ni]);
                }
        }
    }
    int col16 = l & 15, rg = (l >> 4) * 4;
#pragma unroll
    for (int mi = 0; mi < 2; ++mi)
#pragma unroll
        for (int ni = 0; ni < 4; ++ni) {
            int j = nt * 64 + ni * 16 + col16;
            float cl = cLin[j], cg = cG[j];
            size_t row0 = m0 + w * 32 + mi * 16 + rg;
#pragma unroll
            for (int r = 0; r < 4; ++r) {
                float lin = accL[mi][ni][r] + cl;
                float gv = accG[mi][ni][r] + cg;
                float s = 1.0f / (1.0f + __expf(-gv));
                out[(row0 + r) * 1024 + j] = lin * s;
            }
        }
}

// ---- logits -----------------------------------------------------------------
__global__ __launch_bounds__(256) void logits_kernel(
    const ushort_t* __restrict__ Abf, const float* __restrict__ Lw,
    const float* __restrict__ cC, float* __restrict__ out) {
    __shared__ float LwS[3][2048];
    int tid = threadIdx.x;
    for (int idx = tid; idx < 6144; idx += 256) {
        int k = idx / 3, t = idx - 3 * k;
        LwS[t][k] = Lw[idx];
    }
    __syncthreads();
    int w = tid >> 6, l = tid & 63;
    float c0 = cC[0], c1 = cC[1], c2 = cC[2];
    for (int r = 0; r < 4; ++r) {
        int row = blockIdx.x * 16 + w * 4 + r;
        const ushort_t* Ar = Abf + (size_t)row * 2048;
        float a0 = 0.f, a1 = 0.f, a2 = 0.f;
#pragma unroll
        for (int i = 0; i < 16; ++i) {
            int k = 2 * l + 128 * i;
            unsigned int x = *(const unsigned int*)(Ar + k);
            float x0 = bf2f(x & 0xffffu), x1 = bf2f(x >> 16);
            float2 w0 = *(const float2*)&LwS[0][k];
            float2 w1 = *(const float2*)&LwS[1][k];
            float2 w2 = *(const float2*)&LwS[2][k];
            a0 += x0 * w0.x + x1 * w0.y;
            a1 += x0 * w1.x + x1 * w1.y;
            a2 += x0 * w2.x + x1 * w2.y;
        }
#pragma unroll
        for (int off = 32; off; off >>= 1) {
            a0 += __shfl_xor(a0, off);
            a1 += __shfl_xor(a1, off);
            a2 += __shfl_xor(a2, off);
        }
        if (l == 0) {
            size_t ob = (size_t)16777216 + (size_t)row * 3;
            out[ob] = a0 + c0;
            out[ob + 1] = a1 + c1;
            out[ob + 2] = a2 + c2;
        }
    }
}

// ---- launch -----------------------------------------------------------------
extern "C" void kernel_launch(void* const* d_in, const int* in_sizes, int n_in,
                              void* d_out, int out_size, void* d_ws, size_t ws_size,
                              hipStream_t stream) {
    const float* dA = (const float*)d_in[0];
    const float* dB = (const float*)d_in[1];
    const float* Wv = (const float*)d_in[6];
    const float* bv = (const float*)d_in[7];
    const float* Wo = (const float*)d_in[8];
    const float* bo = (const float*)d_in[9];
    const float* Wc = (const float*)d_in[10];
    const float* bc = (const float*)d_in[11];
    const float* Wg = (const float*)d_in[12];
    const float* bg = (const float*)d_in[13];
    float* out = (float*)d_out;

    char* ws = (char*)d_ws;
    ushort_t* Abf  = (ushort_t*)(ws);
    ushort_t* WT   = (ushort_t*)(ws + 67108864);
    ushort_t* Wvbf = (ushort_t*)(ws + 75497472);
    ushort_t* WoT  = (ushort_t*)(ws + 83886080);
    ushort_t* WgT  = (ushort_t*)(ws + 92274688);
    ushort_t* Mbuf = (ushort_t*)(ws + 96468992);
    float* t4   = (float*)(ws + 100663296);
    float* cLin = (float*)(ws + 100679680);
    float* cG   = (float*)(ws + 100683776);
    float* cC   = (float*)(ws + 100687872);
    float* Lw   = (float*)(ws + 100688128);

    // conversions
    convA_kernel<<<16384, 256, 0, stream>>>(dA, dB, Abf);
    convC_kernel<<<2048, 256, 0, stream>>>(Wv, Wvbf);
    convT_kernel<<<dim3(32, 32, 4), 256, 0, stream>>>(Wo, WoT, 1024, 1024, 1048576, 1048576);
    convT_kernel<<<dim3(32, 64, 1), 256, 0, stream>>>(Wg, WgT, 2048, 1024, 0, 0);
    // bias chain t4[g] = bv[g]@Wo[g]+bo[g]
    biasT_kernel<<<16, 256, 0, stream>>>(bv, Wo, bo, t4);
    // merged fold: lin weights (-> WT) and M2'/M3' (-> Mbuf)
    fold_l12<<<dim3(16, 16, 4), 128, 0, stream>>>(Wvbf, WoT, WT, Mbuf);
    // gate weights (-> WT gate rows), needs Mbuf
    fold_l34<<<dim3(16, 16, 2), 128, 0, stream>>>(WgT, Mbuf, WT);
    cgc_kernel<<<4, 256, 0, stream>>>(t4, Wg, bg, cLin, cG);
    ccc_kernel<<<1, 256, 0, stream>>>(t4, Wc, bc, cC);
    lfold_kernel<<<24, 256, 0, stream>>>(Mbuf, Wc, Lw);
    // main fused GEMM + gate epilogue
    main_mm<<<2048, 256, 0, stream>>>(Abf, WT, cLin, cG, out);
    // logits
    logits_kernel<<<1024, 256, 0, stream>>>(Abf, Lw, cC, out);
}

// Round 3
// 492.154 us; speedup vs baseline: 1.3022x; 1.3022x over previous
//
#include <hip/hip_runtime.h>

// DrugInteractionAttention — S=1 attention collapses; everything folds into one
// bf16 MFMA GEMM [16384 x 2048] @ [2048 x 2048] with sigmoid-gate epilogue,
// plus a tiny logits pass. Weight folding (6x 1024^3 GEMMs) done per-call.
//
// ws layout (bytes), total ~100.7 MB:
//   Abf   [16384][2048] bf16 : 0
//   WT    [2048][2048]  bf16 : 67108864   (packed, transposed folded weight)
//   Wvbf  [4][1024][1024]    : 75497472
//   WoT   [4][1024][1024]    : 83886080   (transposed bf16 Wo)
//   WgT   [1024][2048]       : 92274688   (transposed bf16 Wg)
//   Mbuf  [2][1024][1024]    : 96468992   (M2' = Wv2@Wo2, M3' = Wv3@Wo3)
//   t4    [4][1024] f32      : 100663296  (bv[g]@Wo[g]+bo[g], atomic-accum)
//   (gap, was cLin)          : 100679680
//   cG    [1024] f32         : 100683776  (atomic-accum)
//   cC    [3]   f32          : 100687872
//   Lw    [2048][3] f32      : 100688128

typedef unsigned short ushort_t;
typedef __attribute__((ext_vector_type(4))) float f32x4;
typedef __attribute__((ext_vector_type(8))) __bf16 bf16x8;

__device__ __forceinline__ unsigned short f2bf(float f) {
    unsigned int u = __float_as_uint(f);
    u = (u + 0x7fffu + ((u >> 16) & 1u)) >> 16;   // RNE
    return (unsigned short)u;
}
__device__ __forceinline__ float bf2f(unsigned int u) {
    return __uint_as_float(u << 16);
}

// async global->LDS, 16B per lane; LDS dest is wave-uniform base (+lane*16 by HW).
__device__ __forceinline__ void gload16(const void* g, void* l) {
    __builtin_amdgcn_global_load_lds(
        (const __attribute__((address_space(1))) void*)g,
        (__attribute__((address_space(3))) void*)l, 16, 0, 0);
}

__device__ __forceinline__ f32x4 mfma16(bf16x8 a, bf16x8 b, f32x4 c) {
    return __builtin_amdgcn_mfma_f32_16x16x32_bf16(a, b, c, 0, 0, 0);
}

// ---- conversion kernels -----------------------------------------------------

// Abf[i][k] = bf16( k<1024 ? a[i][k] : b[i][k-1024] ), 8 elems/thread
__global__ __launch_bounds__(256) void convA_kernel(
    const float* __restrict__ a, const float* __restrict__ b,
    ushort_t* __restrict__ Abf) {
    int idx = blockIdx.x * 256 + threadIdx.x;          // 4,194,304 threads
    size_t e0 = (size_t)idx * 8;
    int i = (int)(e0 >> 11);
    int k = (int)(e0 & 2047);
    const float* src = (k < 1024) ? (a + (size_t)i * 1024 + k)
                                  : (b + (size_t)i * 1024 + (k - 1024));
    float4 f0 = ((const float4*)src)[0];
    float4 f1 = ((const float4*)src)[1];
    uint4 o;
    o.x = (unsigned)f2bf(f0.x) | ((unsigned)f2bf(f0.y) << 16);
    o.y = (unsigned)f2bf(f0.z) | ((unsigned)f2bf(f0.w) << 16);
    o.z = (unsigned)f2bf(f1.x) | ((unsigned)f2bf(f1.y) << 16);
    o.w = (unsigned)f2bf(f1.z) | ((unsigned)f2bf(f1.w) << 16);
    *(uint4*)(Abf + e0) = o;
}

// straight f32 -> bf16 copy (Wv, 4M elems)
__global__ __launch_bounds__(256) void convC_kernel(
    const float* __restrict__ src, ushort_t* __restrict__ dst) {
    size_t e0 = ((size_t)blockIdx.x * 256 + threadIdx.x) * 8;
    float4 f0 = ((const float4*)(src + e0))[0];
    float4 f1 = ((const float4*)(src + e0))[1];
    uint4 o;
    o.x = (unsigned)f2bf(f0.x) | ((unsigned)f2bf(f0.y) << 16);
    o.y = (unsigned)f2bf(f0.z) | ((unsigned)f2bf(f0.w) << 16);
    o.z = (unsigned)f2bf(f1.x) | ((unsigned)f2bf(f1.y) << 16);
    o.w = (unsigned)f2bf(f1.z) | ((unsigned)f2bf(f1.w) << 16);
    *(uint4*)(dst + e0) = o;
}

// transpose f32 [R][C] -> bf16 [C][R], 32x32 tiles, z-batched
__global__ __launch_bounds__(256) void convT_kernel(
    const float* __restrict__ src, ushort_t* __restrict__ dst,
    int R, int C, long zs, long zd) {
    __shared__ float tile[32][33];
    int tx = threadIdx.x & 31, ty = threadIdx.x >> 5;  // ty 0..7
    const float* s = src + (size_t)blockIdx.z * zs;
    ushort_t* d = dst + (size_t)blockIdx.z * zd;
    int r0 = blockIdx.y * 32, c0 = blockIdx.x * 32;
#pragma unroll
    for (int p = 0; p < 4; ++p)
        tile[p * 8 + ty][tx] = s[(size_t)(r0 + p * 8 + ty) * C + c0 + tx];
    __syncthreads();
#pragma unroll
    for (int p = 0; p < 4; ++p)
        d[(size_t)(c0 + p * 8 + ty) * R + r0 + tx] = f2bf(tile[tx][p * 8 + ty]);
}

// ---- bias chains (parallelized) ---------------------------------------------

// t4[g][j] += partial of bv[g]@Wo[g] (+bo in chunk 0); t4 pre-zeroed.
// grid 128: g = bx>>5, jt = (bx>>3)&3, kc = bx&7
__global__ __launch_bounds__(256) void biasT2_kernel(
    const float* __restrict__ bv, const float* __restrict__ Wo,
    const float* __restrict__ bo, float* __restrict__ t4) {
    int bx = blockIdx.x;
    int g = bx >> 5, jt = (bx >> 3) & 3, kc = bx & 7;
    int j = jt * 256 + threadIdx.x;
    const float* W = Wo + (size_t)g * 1048576;
    const float* v = bv + g * 1024;
    float acc = (kc == 0) ? bo[g * 1024 + j] : 0.f;
    int k0 = kc * 128;
    for (int k = k0; k < k0 + 128; ++k)
        acc += v[k] * W[(size_t)k * 1024 + j];
    atomicAdd(&t4[g * 1024 + j], acc);
}

// blocks 0..63: cG[j] += partial of [t2|t3]@Wg (+bg in chunk 0); cG pre-zeroed.
// block 64: cC[t] = [t2|t3]@Wc + bc
__global__ __launch_bounds__(256) void post_kernel(
    const float* __restrict__ t4, const float* __restrict__ Wg,
    const float* __restrict__ bg, const float* __restrict__ Wc,
    const float* __restrict__ bc, float* __restrict__ cG,
    float* __restrict__ cC) {
    if (blockIdx.x < 64) {
        int jt = blockIdx.x >> 4, kc = blockIdx.x & 15;
        int j = jt * 256 + threadIdx.x;
        float acc = (kc == 0) ? bg[j] : 0.f;
        int k0 = kc * 128;
        for (int k = k0; k < k0 + 128; ++k)
            acc += t4[2048 + k] * Wg[(size_t)k * 1024 + j];
        atomicAdd(&cG[j], acc);
    } else {
        __shared__ float red[192];
        int tid = threadIdx.x;
        if (tid < 192) {
            int t = tid % 3, c = tid / 3;   // c 0..63
            float acc = 0.f;
            for (int kk = 0; kk < 32; ++kk) {
                int k = c * 32 + kk;
                acc += t4[2048 + k] * Wc[(size_t)k * 3 + t];
            }
            red[tid] = acc;
        }
        __syncthreads();
        if (tid < 3) {
            float s = bc[tid];
            for (int c = 0; c < 64; ++c) s += red[tid + 3 * c];
            cC[tid] = s;
        }
    }
}

// Lw[h*1024+k][t] = sum_m Mbuf[sel_h][k][m] * Wc_h[m][t]; wave per (h,k)
__global__ __launch_bounds__(256) void lfold2_kernel(
    const ushort_t* __restrict__ Mbuf, const float* __restrict__ Wc,
    float* __restrict__ Lw) {
    int wid = blockIdx.x * 4 + (threadIdx.x >> 6);   // 0..2047
    int l = threadIdx.x & 63;
    int h = wid >> 10, k = wid & 1023;
    const ushort_t* Mrow = Mbuf + (h == 0 ? 1048576 : 0) + (size_t)k * 1024;
    const float* Wcp = Wc + (h == 0 ? 3072 : 0);
    float a0 = 0.f, a1 = 0.f, a2 = 0.f;
#pragma unroll 4
    for (int i = 0; i < 16; ++i) {
        int m = i * 64 + l;
        float x = bf2f((unsigned)Mrow[m]);
        const float* wp = Wcp + (size_t)m * 3;
        a0 += x * wp[0];
        a1 += x * wp[1];
        a2 += x * wp[2];
    }
#pragma unroll
    for (int off = 32; off; off >>= 1) {
        a0 += __shfl_xor(a0, off);
        a1 += __shfl_xor(a1, off);
        a2 += __shfl_xor(a2, off);
    }
    if (l == 0) {
        float* o = Lw + (size_t)(h * 1024 + k) * 3;
        o[0] = a0; o[1] = a1; o[2] = a2;
    }
}

// ---- fold GEMM body (NT, 64x64x64 tiles, 2 waves, K=1024) -------------------
// C[m][n] = sum_q A[m][q] * BT[n][q], output bf16 with row remap:
//   rowMode 0: orow=m   1: (m>>6)*128+(m&63)   2: (m>>6)*128+64+(m&63)
__device__ __forceinline__ void fold_body(
    ushort_t* sA, ushort_t* sB,
    const ushort_t* __restrict__ A, int lda,
    const ushort_t* __restrict__ BT, int ldbt,
    ushort_t* __restrict__ ob, int ldout, int rowMode, int colOff,
    int bx, int by) {
    int tid = threadIdx.x, w = tid >> 6, l = tid & 63;
    f32x4 acc[2][4];
#pragma unroll
    for (int i = 0; i < 2; ++i)
#pragma unroll
        for (int j = 0; j < 4; ++j) acc[i][j] = (f32x4){0.f, 0.f, 0.f, 0.f};
    int srow = l >> 3, skoff = (l & 7) * 8;
    const ushort_t* Abase = A + (size_t)(by * 64 + w * 32 + srow) * lda + skoff;
    const ushort_t* Bbase = BT + (size_t)(bx * 64 + w * 32 + srow) * ldbt + skoff;
    for (int k0 = 0; k0 < 1024; k0 += 64) {
        __syncthreads();
#pragma unroll
        for (int i = 0; i < 4; ++i) {
            gload16(Abase + (size_t)i * 8 * lda + k0, &sA[(w * 32 + i * 8) * 64]);
            gload16(Bbase + (size_t)i * 8 * ldbt + k0, &sB[(w * 32 + i * 8) * 64]);
        }
        __syncthreads();
#pragma unroll
        for (int kk = 0; kk < 2; ++kk) {
            int kb = kk * 32 + (l >> 4) * 8;
            bf16x8 aF[2], bF[4];
#pragma unroll
            for (int mi = 0; mi < 2; ++mi)
                aF[mi] = *(const bf16x8*)&sA[(w * 32 + mi * 16 + (l & 15)) * 64 + kb];
#pragma unroll
            for (int ni = 0; ni < 4; ++ni)
                bF[ni] = *(const bf16x8*)&sB[(ni * 16 + (l & 15)) * 64 + kb];
#pragma unroll
            for (int mi = 0; mi < 2; ++mi)
#pragma unroll
                for (int ni = 0; ni < 4; ++ni)
                    acc[mi][ni] = mfma16(aF[mi], bF[ni], acc[mi][ni]);
        }
    }
    int col16 = l & 15, rg = (l >> 4) * 4;
#pragma unroll
    for (int mi = 0; mi < 2; ++mi)
#pragma unroll
        for (int ni = 0; ni < 4; ++ni) {
            int n = bx * 64 + ni * 16 + col16;
#pragma unroll
            for (int r = 0; r < 4; ++r) {
                int m = by * 64 + w * 32 + mi * 16 + rg + r;
                int orow = (rowMode == 0)
                               ? m
                               : ((m >> 6) * 128 + (rowMode == 2 ? 64 : 0) + (m & 63));
                ob[(size_t)orow * ldout + colOff + n] = f2bf(acc[mi][ni][r]);
            }
        }
}

// merged L1+L2: z=0,1 -> WT lin rows (M'^T, rowMode1); z=2,3 -> Mbuf (M', rowMode0)
__global__ __launch_bounds__(128) void fold_l12(
    const ushort_t* __restrict__ Wvbf, const ushort_t* __restrict__ WoT,
    ushort_t* __restrict__ WT, ushort_t* __restrict__ Mbuf) {
    __shared__ alignas(16) ushort_t sA[64 * 64];
    __shared__ alignas(16) ushort_t sB[64 * 64];
    int z = blockIdx.z;
    const ushort_t *A, *BT;
    ushort_t* ob;
    int rowMode, colOff, ldout;
    if (z < 2) {   // C = M_z'^T -> WT lin, cols z*1024..
        A = WoT + (size_t)z * 1048576;
        BT = Wvbf + (size_t)z * 1048576;
        ob = WT; rowMode = 1; colOff = z * 1024; ldout = 2048;
    } else {       // C = M_z' -> Mbuf[z-2]
        A = Wvbf + (size_t)z * 1048576;
        BT = WoT + (size_t)z * 1048576;
        ob = Mbuf + (size_t)(z - 2) * 1048576; rowMode = 0; colOff = 0; ldout = 1024;
    }
    fold_body(sA, sB, A, 1024, BT, 1024, ob, ldout, rowMode, colOff,
              blockIdx.x, blockIdx.y);
}

// L34: z=0 gate-a = NT(WgT[:,1024:], M3') -> WT gate cols 0..1023 (rowMode2)
//      z=1 gate-b = NT(WgT[:,0:1024], M2') -> WT gate cols 1024..2047
__global__ __launch_bounds__(128) void fold_l34(
    const ushort_t* __restrict__ WgT, const ushort_t* __restrict__ Mbuf,
    ushort_t* __restrict__ WT) {
    __shared__ alignas(16) ushort_t sA[64 * 64];
    __shared__ alignas(16) ushort_t sB[64 * 64];
    int z = blockIdx.z;
    const ushort_t* A = WgT + (z == 0 ? 1024 : 0);
    const ushort_t* BT = Mbuf + (z == 0 ? 1048576 : 0);
    fold_body(sA, sB, A, 2048, BT, 1024, WT, 2048, 2, z * 1024,
              blockIdx.x, blockIdx.y);
}

// ---- main fused GEMM (128x128x64, 4 waves) ----------------------------------
// A [16384][2048] bf16, WT [2048][2048] bf16 packed: tile nt's 128 rows are
// 64 lin cols then 64 gate cols (j = nt*64+c). Each wave computes 32 rows x
// all 64 j, lin+gate accs in-register, epilogue fuses sigmoid gate.
__global__ __launch_bounds__(256) void main_mm(
    const ushort_t* __restrict__ A, const ushort_t* __restrict__ WT,
    const float* __restrict__ t4, const float* __restrict__ cG,
    float* __restrict__ out) {
    __shared__ alignas(16) ushort_t sA[128 * 64];
    __shared__ alignas(16) ushort_t sB[128 * 64];
    int tid = threadIdx.x, w = tid >> 6, l = tid & 63;
    int bid = blockIdx.x;
    int swz = ((bid & 7) << 8) | (bid >> 3);   // 2048 wgs, 8 XCDs, bijective
    int mt = swz >> 4, nt = swz & 15;
    size_t m0 = (size_t)mt * 128;
    f32x4 accL[2][4], accG[2][4];
#pragma unroll
    for (int i = 0; i < 2; ++i)
#pragma unroll
        for (int j = 0; j < 4; ++j) {
            accL[i][j] = (f32x4){0.f, 0.f, 0.f, 0.f};
            accG[i][j] = (f32x4){0.f, 0.f, 0.f, 0.f};
        }
    int srow = l >> 3, skoff = (l & 7) * 8;
    const ushort_t* Abase = A + (m0 + w * 32 + srow) * 2048 + skoff;
    const ushort_t* Bbase = WT + ((size_t)nt * 128 + w * 32 + srow) * 2048 + skoff;
    for (int k0 = 0; k0 < 2048; k0 += 64) {
        __syncthreads();
#pragma unroll
        for (int i = 0; i < 4; ++i) {
            gload16(Abase + (size_t)i * 8 * 2048 + k0, &sA[(w * 32 + i * 8) * 64]);
            gload16(Bbase + (size_t)i * 8 * 2048 + k0, &sB[(w * 32 + i * 8) * 64]);
        }
        __syncthreads();
#pragma unroll
        for (int kk = 0; kk < 2; ++kk) {
            int kb = kk * 32 + (l >> 4) * 8;
            bf16x8 aF[2], bF[8];
#pragma unroll
            for (int mi = 0; mi < 2; ++mi)
                aF[mi] = *(const bf16x8*)&sA[(w * 32 + mi * 16 + (l & 15)) * 64 + kb];
#pragma unroll
            for (int ni = 0; ni < 8; ++ni)
                bF[ni] = *(const bf16x8*)&sB[(ni * 16 + (l & 15)) * 64 + kb];
#pragma unroll
            for (int mi = 0; mi < 2; ++mi)
#pragma unroll
                for (int ni = 0; ni < 4; ++ni) {
                    accL[mi][ni] = mfma16(aF[mi], bF[ni], accL[mi][ni]);
                    accG[mi][ni] = mfma16(aF[mi], bF[4 + ni], accG[mi][ni]);
                }
        }
    }
    int col16 = l & 15, rg = (l >> 4) * 4;
#pragma unroll
    for (int mi = 0; mi < 2; ++mi)
#pragma unroll
        for (int ni = 0; ni < 4; ++ni) {
            int j = nt * 64 + ni * 16 + col16;
            float cl = t4[j] + t4[1024 + j];
            float cg = cG[j];
            size_t row0 = m0 + w * 32 + mi * 16 + rg;
#pragma unroll
            for (int r = 0; r < 4; ++r) {
                float lin = accL[mi][ni][r] + cl;
                float gv = accG[mi][ni][r] + cg;
                float s = 1.0f / (1.0f + __expf(-gv));
                out[(row0 + r) * 1024 + j] = lin * s;
            }
        }
}

// ---- logits -----------------------------------------------------------------
__global__ __launch_bounds__(256) void logits_kernel(
    const ushort_t* __restrict__ Abf, const float* __restrict__ Lw,
    const float* __restrict__ cC, float* __restrict__ out) {
    __shared__ float LwS[3][2048];
    int tid = threadIdx.x;
    for (int idx = tid; idx < 6144; idx += 256) {
        int k = idx / 3, t = idx - 3 * k;
        LwS[t][k] = Lw[idx];
    }
    __syncthreads();
    int w = tid >> 6, l = tid & 63;
    float c0 = cC[0], c1 = cC[1], c2 = cC[2];
    for (int r = 0; r < 4; ++r) {
        int row = blockIdx.x * 16 + w * 4 + r;
        const ushort_t* Ar = Abf + (size_t)row * 2048;
        float a0 = 0.f, a1 = 0.f, a2 = 0.f;
#pragma unroll
        for (int i = 0; i < 16; ++i) {
            int k = 2 * l + 128 * i;
            unsigned int x = *(const unsigned int*)(Ar + k);
            float x0 = bf2f(x & 0xffffu), x1 = bf2f(x >> 16);
            float2 w0 = *(const float2*)&LwS[0][k];
            float2 w1 = *(const float2*)&LwS[1][k];
            float2 w2 = *(const float2*)&LwS[2][k];
            a0 += x0 * w0.x + x1 * w0.y;
            a1 += x0 * w1.x + x1 * w1.y;
            a2 += x0 * w2.x + x1 * w2.y;
        }
#pragma unroll
        for (int off = 32; off; off >>= 1) {
            a0 += __shfl_xor(a0, off);
            a1 += __shfl_xor(a1, off);
            a2 += __shfl_xor(a2, off);
        }
        if (l == 0) {
            size_t ob = (size_t)16777216 + (size_t)row * 3;
            out[ob] = a0 + c0;
            out[ob + 1] = a1 + c1;
            out[ob + 2] = a2 + c2;
        }
    }
}

// ---- launch -----------------------------------------------------------------
extern "C" void kernel_launch(void* const* d_in, const int* in_sizes, int n_in,
                              void* d_out, int out_size, void* d_ws, size_t ws_size,
                              hipStream_t stream) {
    const float* dA = (const float*)d_in[0];
    const float* dB = (const float*)d_in[1];
    const float* Wv = (const float*)d_in[6];
    const float* bv = (const float*)d_in[7];
    const float* Wo = (const float*)d_in[8];
    const float* bo = (const float*)d_in[9];
    const float* Wc = (const float*)d_in[10];
    const float* bc = (const float*)d_in[11];
    const float* Wg = (const float*)d_in[12];
    const float* bg = (const float*)d_in[13];
    float* out = (float*)d_out;

    char* ws = (char*)d_ws;
    ushort_t* Abf  = (ushort_t*)(ws);
    ushort_t* WT   = (ushort_t*)(ws + 67108864);
    ushort_t* Wvbf = (ushort_t*)(ws + 75497472);
    ushort_t* WoT  = (ushort_t*)(ws + 83886080);
    ushort_t* WgT  = (ushort_t*)(ws + 92274688);
    ushort_t* Mbuf = (ushort_t*)(ws + 96468992);
    float* t4   = (float*)(ws + 100663296);
    float* cG   = (float*)(ws + 100683776);
    float* cC   = (float*)(ws + 100687872);
    float* Lw   = (float*)(ws + 100688128);

    // conversions
    convA_kernel<<<16384, 256, 0, stream>>>(dA, dB, Abf);
    convC_kernel<<<2048, 256, 0, stream>>>(Wv, Wvbf);
    convT_kernel<<<dim3(32, 32, 4), 256, 0, stream>>>(Wo, WoT, 1024, 1024, 1048576, 1048576);
    convT_kernel<<<dim3(32, 64, 1), 256, 0, stream>>>(Wg, WgT, 2048, 1024, 0, 0);
    // zero atomic accumulators (t4 .. cC region)
    hipMemsetAsync(ws + 100663296, 0, 24832, stream);
    // t4[g] = bv[g]@Wo[g]+bo[g], 128-block atomic version
    biasT2_kernel<<<128, 256, 0, stream>>>(bv, Wo, bo, t4);
    // merged fold: lin weights (-> WT) and M2'/M3' (-> Mbuf)
    fold_l12<<<dim3(16, 16, 4), 128, 0, stream>>>(Wvbf, WoT, WT, Mbuf);
    // gate weights (-> WT gate rows), needs Mbuf
    fold_l34<<<dim3(16, 16, 2), 128, 0, stream>>>(WgT, Mbuf, WT);
    // cG (atomic, 64 blocks) + cC (block 64); needs t4
    post_kernel<<<65, 256, 0, stream>>>(t4, Wg, bg, Wc, bc, cG, cC);
    // Lw: wave per (half,k); needs Mbuf
    lfold2_kernel<<<512, 256, 0, stream>>>(Mbuf, Wc, Lw);
    // main fused GEMM + gate epilogue (reads t4, cG directly)
    main_mm<<<2048, 256, 0, stream>>>(Abf, WT, t4, cG, out);
    // logits
    logits_kernel<<<1024, 256, 0, stream>>>(Abf, Lw, cC, out);
}

// Round 4
// 435.330 us; speedup vs baseline: 1.4722x; 1.1305x over previous
//
#include <hip/hip_runtime.h>

// DrugInteractionAttention — S=1 attention collapses; everything folds into one
// bf16 MFMA GEMM [16384 x 2048] @ [2048 x 2048] with sigmoid-gate epilogue,
// plus a tiny logits pass. Weight folding (6x 1024^3 GEMMs) done per-call.
//
// main_mm: 256x256x64 8-wave 4-phase pipelined schedule (m201 template),
// T2 LDS XOR-swizzle (blk ^= row&7) via pre-swizzled global source,
// counted staging with vmcnt(0) only at tile boundary, setprio around MFMA.
//
// WT packing: 64-row groups = 32 lin rows + 32 gate rows for the same j's,
// so each wave holds lin+gate pairs in-register for the epilogue.
//
// ws layout (bytes), total ~100.7 MB:
//   Abf   [16384][2048] bf16 : 0
//   WT    [2048][2048]  bf16 : 67108864
//   Wvbf  [4][1024][1024]    : 75497472
//   WoT   [4][1024][1024]    : 83886080
//   WgT   [1024][2048]       : 92274688
//   Mbuf  [2][1024][1024]    : 96468992
//   t4    [4][1024] f32      : 100663296 (atomic-accum)
//   cG    [1024] f32         : 100683776 (atomic-accum)
//   cC    [3]   f32          : 100687872
//   Lw    [2048][3] f32      : 100688128

typedef unsigned short ushort_t;
typedef __attribute__((ext_vector_type(4))) float f32x4;
typedef __attribute__((ext_vector_type(8))) __bf16 bf16x8;

__device__ __forceinline__ unsigned short f2bf(float f) {
    unsigned int u = __float_as_uint(f);
    u = (u + 0x7fffu + ((u >> 16) & 1u)) >> 16;   // RNE
    return (unsigned short)u;
}
__device__ __forceinline__ float bf2f(unsigned int u) {
    return __uint_as_float(u << 16);
}

__device__ __forceinline__ void gload16(const void* g, void* l) {
    __builtin_amdgcn_global_load_lds(
        (const __attribute__((address_space(1))) void*)g,
        (__attribute__((address_space(3))) void*)l, 16, 0, 0);
}

__device__ __forceinline__ f32x4 mfma16(bf16x8 a, bf16x8 b, f32x4 c) {
    return __builtin_amdgcn_mfma_f32_16x16x32_bf16(a, b, c, 0, 0, 0);
}

// ---- conversion kernels -----------------------------------------------------

__global__ __launch_bounds__(256) void convA_kernel(
    const float* __restrict__ a, const float* __restrict__ b,
    ushort_t* __restrict__ Abf) {
    int idx = blockIdx.x * 256 + threadIdx.x;
    size_t e0 = (size_t)idx * 8;
    int i = (int)(e0 >> 11);
    int k = (int)(e0 & 2047);
    const float* src = (k < 1024) ? (a + (size_t)i * 1024 + k)
                                  : (b + (size_t)i * 1024 + (k - 1024));
    float4 f0 = ((const float4*)src)[0];
    float4 f1 = ((const float4*)src)[1];
    uint4 o;
    o.x = (unsigned)f2bf(f0.x) | ((unsigned)f2bf(f0.y) << 16);
    o.y = (unsigned)f2bf(f0.z) | ((unsigned)f2bf(f0.w) << 16);
    o.z = (unsigned)f2bf(f1.x) | ((unsigned)f2bf(f1.y) << 16);
    o.w = (unsigned)f2bf(f1.z) | ((unsigned)f2bf(f1.w) << 16);
    *(uint4*)(Abf + e0) = o;
}

__global__ __launch_bounds__(256) void convC_kernel(
    const float* __restrict__ src, ushort_t* __restrict__ dst) {
    size_t e0 = ((size_t)blockIdx.x * 256 + threadIdx.x) * 8;
    float4 f0 = ((const float4*)(src + e0))[0];
    float4 f1 = ((const float4*)(src + e0))[1];
    uint4 o;
    o.x = (unsigned)f2bf(f0.x) | ((unsigned)f2bf(f0.y) << 16);
    o.y = (unsigned)f2bf(f0.z) | ((unsigned)f2bf(f0.w) << 16);
    o.z = (unsigned)f2bf(f1.x) | ((unsigned)f2bf(f1.y) << 16);
    o.w = (unsigned)f2bf(f1.z) | ((unsigned)f2bf(f1.w) << 16);
    *(uint4*)(dst + e0) = o;
}

__global__ __launch_bounds__(256) void convT_kernel(
    const float* __restrict__ src, ushort_t* __restrict__ dst,
    int R, int C, long zs, long zd) {
    __shared__ float tile[32][33];
    int tx = threadIdx.x & 31, ty = threadIdx.x >> 5;
    const float* s = src + (size_t)blockIdx.z * zs;
    ushort_t* d = dst + (size_t)blockIdx.z * zd;
    int r0 = blockIdx.y * 32, c0 = blockIdx.x * 32;
#pragma unroll
    for (int p = 0; p < 4; ++p)
        tile[p * 8 + ty][tx] = s[(size_t)(r0 + p * 8 + ty) * C + c0 + tx];
    __syncthreads();
#pragma unroll
    for (int p = 0; p < 4; ++p)
        d[(size_t)(c0 + p * 8 + ty) * R + r0 + tx] = f2bf(tile[tx][p * 8 + ty]);
}

// ---- bias chains ------------------------------------------------------------

__global__ __launch_bounds__(256) void biasT2_kernel(
    const float* __restrict__ bv, const float* __restrict__ Wo,
    const float* __restrict__ bo, float* __restrict__ t4) {
    int bx = blockIdx.x;
    int g = bx >> 5, jt = (bx >> 3) & 3, kc = bx & 7;
    int j = jt * 256 + threadIdx.x;
    const float* W = Wo + (size_t)g * 1048576;
    const float* v = bv + g * 1024;
    float acc = (kc == 0) ? bo[g * 1024 + j] : 0.f;
    int k0 = kc * 128;
    for (int k = k0; k < k0 + 128; ++k)
        acc += v[k] * W[(size_t)k * 1024 + j];
    atomicAdd(&t4[g * 1024 + j], acc);
}

__global__ __launch_bounds__(256) void post_kernel(
    const float* __restrict__ t4, const float* __restrict__ Wg,
    const float* __restrict__ bg, const float* __restrict__ Wc,
    const float* __restrict__ bc, float* __restrict__ cG,
    float* __restrict__ cC) {
    if (blockIdx.x < 64) {
        int jt = blockIdx.x >> 4, kc = blockIdx.x & 15;
        int j = jt * 256 + threadIdx.x;
        float acc = (kc == 0) ? bg[j] : 0.f;
        int k0 = kc * 128;
        for (int k = k0; k < k0 + 128; ++k)
            acc += t4[2048 + k] * Wg[(size_t)k * 1024 + j];
        atomicAdd(&cG[j], acc);
    } else {
        __shared__ float red[192];
        int tid = threadIdx.x;
        if (tid < 192) {
            int t = tid % 3, c = tid / 3;
            float acc = 0.f;
            for (int kk = 0; kk < 32; ++kk) {
                int k = c * 32 + kk;
                acc += t4[2048 + k] * Wc[(size_t)k * 3 + t];
            }
            red[tid] = acc;
        }
        __syncthreads();
        if (tid < 3) {
            float s = bc[tid];
            for (int c = 0; c < 64; ++c) s += red[tid + 3 * c];
            cC[tid] = s;
        }
    }
}

__global__ __launch_bounds__(256) void lfold2_kernel(
    const ushort_t* __restrict__ Mbuf, const float* __restrict__ Wc,
    float* __restrict__ Lw) {
    int wid = blockIdx.x * 4 + (threadIdx.x >> 6);
    int l = threadIdx.x & 63;
    int h = wid >> 10, k = wid & 1023;
    const ushort_t* Mrow = Mbuf + (h == 0 ? 1048576 : 0) + (size_t)k * 1024;
    const float* Wcp = Wc + (h == 0 ? 3072 : 0);
    float a0 = 0.f, a1 = 0.f, a2 = 0.f;
#pragma unroll 4
    for (int i = 0; i < 16; ++i) {
        int m = i * 64 + l;
        float x = bf2f((unsigned)Mrow[m]);
        const float* wp = Wcp + (size_t)m * 3;
        a0 += x * wp[0];
        a1 += x * wp[1];
        a2 += x * wp[2];
    }
#pragma unroll
    for (int off = 32; off; off >>= 1) {
        a0 += __shfl_xor(a0, off);
        a1 += __shfl_xor(a1, off);
        a2 += __shfl_xor(a2, off);
    }
    if (l == 0) {
        float* o = Lw + (size_t)(h * 1024 + k) * 3;
        o[0] = a0; o[1] = a1; o[2] = a2;
    }
}

// ---- fold GEMM body (NT, 64x64x64 tiles, 2 waves, K=1024) -------------------
// C[m][n] = sum_q A[m][q]*BT[n][q], bf16 out. Row remap for WT 64-row packing:
//   rowMode 0: orow=m
//   rowMode 1 (lin):  orow = (m>>5)*64 + (m&31)
//   rowMode 2 (gate): orow = (m>>5)*64 + 32 + (m&31)
__device__ __forceinline__ void fold_body(
    ushort_t* sA, ushort_t* sB,
    const ushort_t* __restrict__ A, int lda,
    const ushort_t* __restrict__ BT, int ldbt,
    ushort_t* __restrict__ ob, int ldout, int rowMode, int colOff,
    int bx, int by) {
    int tid = threadIdx.x, w = tid >> 6, l = tid & 63;
    f32x4 acc[2][4];
#pragma unroll
    for (int i = 0; i < 2; ++i)
#pragma unroll
        for (int j = 0; j < 4; ++j) acc[i][j] = (f32x4){0.f, 0.f, 0.f, 0.f};
    int srow = l >> 3, skoff = (l & 7) * 8;
    const ushort_t* Abase = A + (size_t)(by * 64 + w * 32 + srow) * lda + skoff;
    const ushort_t* Bbase = BT + (size_t)(bx * 64 + w * 32 + srow) * ldbt + skoff;
    for (int k0 = 0; k0 < 1024; k0 += 64) {
        __syncthreads();
#pragma unroll
        for (int i = 0; i < 4; ++i) {
            gload16(Abase + (size_t)i * 8 * lda + k0, &sA[(w * 32 + i * 8) * 64]);
            gload16(Bbase + (size_t)i * 8 * ldbt + k0, &sB[(w * 32 + i * 8) * 64]);
        }
        __syncthreads();
#pragma unroll
        for (int kk = 0; kk < 2; ++kk) {
            int kb = kk * 32 + (l >> 4) * 8;
            bf16x8 aF[2], bF[4];
#pragma unroll
            for (int mi = 0; mi < 2; ++mi)
                aF[mi] = *(const bf16x8*)&sA[(w * 32 + mi * 16 + (l & 15)) * 64 + kb];
#pragma unroll
            for (int ni = 0; ni < 4; ++ni)
                bF[ni] = *(const bf16x8*)&sB[(ni * 16 + (l & 15)) * 64 + kb];
#pragma unroll
            for (int mi = 0; mi < 2; ++mi)
#pragma unroll
                for (int ni = 0; ni < 4; ++ni)
                    acc[mi][ni] = mfma16(aF[mi], bF[ni], acc[mi][ni]);
        }
    }
    int col16 = l & 15, rg = (l >> 4) * 4;
#pragma unroll
    for (int mi = 0; mi < 2; ++mi)
#pragma unroll
        for (int ni = 0; ni < 4; ++ni) {
            int n = bx * 64 + ni * 16 + col16;
#pragma unroll
            for (int r = 0; r < 4; ++r) {
                int m = by * 64 + w * 32 + mi * 16 + rg + r;
                int orow = (rowMode == 0)
                               ? m
                               : ((m >> 5) * 64 + (rowMode == 2 ? 32 : 0) + (m & 31));
                ob[(size_t)orow * ldout + colOff + n] = f2bf(acc[mi][ni][r]);
            }
        }
}

__global__ __launch_bounds__(128) void fold_l12(
    const ushort_t* __restrict__ Wvbf, const ushort_t* __restrict__ WoT,
    ushort_t* __restrict__ WT, ushort_t* __restrict__ Mbuf) {
    __shared__ alignas(16) ushort_t sA[64 * 64];
    __shared__ alignas(16) ushort_t sB[64 * 64];
    int z = blockIdx.z;
    const ushort_t *A, *BT;
    ushort_t* ob;
    int rowMode, colOff, ldout;
    if (z < 2) {
        A = WoT + (size_t)z * 1048576;
        BT = Wvbf + (size_t)z * 1048576;
        ob = WT; rowMode = 1; colOff = z * 1024; ldout = 2048;
    } else {
        A = Wvbf + (size_t)z * 1048576;
        BT = WoT + (size_t)z * 1048576;
        ob = Mbuf + (size_t)(z - 2) * 1048576; rowMode = 0; colOff = 0; ldout = 1024;
    }
    fold_body(sA, sB, A, 1024, BT, 1024, ob, ldout, rowMode, colOff,
              blockIdx.x, blockIdx.y);
}

__global__ __launch_bounds__(128) void fold_l34(
    const ushort_t* __restrict__ WgT, const ushort_t* __restrict__ Mbuf,
    ushort_t* __restrict__ WT) {
    __shared__ alignas(16) ushort_t sA[64 * 64];
    __shared__ alignas(16) ushort_t sB[64 * 64];
    int z = blockIdx.z;
    const ushort_t* A = WgT + (z == 0 ? 1024 : 0);
    const ushort_t* BT = Mbuf + (z == 0 ? 1048576 : 0);
    fold_body(sA, sB, A, 2048, BT, 1024, WT, 2048, 2, z * 1024,
              blockIdx.x, blockIdx.y);
}

// ---- main fused GEMM: 256x256x64, 8 waves, 4-phase pipelined ----------------
// A [16384][2048], WT [2048][2048] packed in 64-row groups (32 lin + 32 gate).
// Per block: 32 K-tiles; per tile 4 phases; phase p: ds_read quadrant p
// (+all B in p0), issue 1 half-tile prefetch of tile t+1, barrier, lgkmcnt(0),
// setprio(1), 16 MFMA, setprio(0), barrier. vmcnt(0) only at tile boundary.
// LDS rows (128B) XOR-swizzled: block c at row r stored at c^(r&7), realized
// by pre-swizzling the per-lane GLOBAL source (gload_lds dest stays linear).
__global__ __launch_bounds__(512, 2) void main_mm(
    const ushort_t* __restrict__ A, const ushort_t* __restrict__ WT,
    const float* __restrict__ t4, const float* __restrict__ cG,
    float* __restrict__ out) {
    __shared__ alignas(16) ushort_t sA[2][256 * 64];
    __shared__ alignas(16) ushort_t sB[2][256 * 64];
    const int tid = threadIdx.x;
    const int w = tid >> 6, l = tid & 63;
    const int wr = w >> 2, wc = w & 3;
    // XCD swizzle: 512 wgs, 8 XCDs, 64/XCD; within chunk: mt-major, 8 nt's
    const int bid = blockIdx.x;
    const int idx = (bid & 7) * 64 + (bid >> 3);
    const int mt = idx >> 3, ntb = idx & 7;
    const size_t m0 = (size_t)mt * 256;
    const size_t n0 = (size_t)ntb * 256;

    // staging: wave w instr i covers rows w*16+i*8..+8 of a 128-row half-tile;
    // lane l -> row +(l>>3), dest 16B-block (l&7); source block pre-swizzled.
    const int csrc = (((l & 7) ^ (l >> 3)) * 8);                 // elems
    const ushort_t* gA0 = A  + (m0 + w * 16 + (l >> 3)) * 2048 + csrc;
    const ushort_t* gB0 = WT + (n0 + w * 16 + (l >> 3)) * 2048 + csrc;

#define STAGE_A(b, h, ko)                                                      \
    do {                                                                       \
        gload16(gA0 + (size_t)(h) * 262144 + (ko),                             \
                &sA[b][((h) * 128 + w * 16) * 64]);                            \
        gload16(gA0 + (size_t)(h) * 262144 + 16384 + (ko),                     \
                &sA[b][((h) * 128 + w * 16 + 8) * 64]);                        \
    } while (0)
#define STAGE_B(b, h, ko)                                                      \
    do {                                                                       \
        gload16(gB0 + (size_t)(h) * 262144 + (ko),                             \
                &sB[b][((h) * 128 + w * 16) * 64]);                            \
        gload16(gB0 + (size_t)(h) * 262144 + 16384 + (ko),                     \
                &sB[b][((h) * 128 + w * 16 + 8) * 64]);                        \
    } while (0)

    // frag-read bases: row rb + q*16, col (s*32 + (l>>4)*8) ^ ((l&7)<<3)
    const int rbA = wr * 128 + (l & 15);
    const int rbB = wc * 64 + (l & 15);
    const int cxor = (l & 7) << 3;
    const int c0 = ((l >> 4) * 8) ^ cxor;
    const int c1 = (32 + (l >> 4) * 8) ^ cxor;

    f32x4 acc[8][4];
#pragma unroll
    for (int i = 0; i < 8; ++i)
#pragma unroll
        for (int j = 0; j < 4; ++j) acc[i][j] = (f32x4){0.f, 0.f, 0.f, 0.f};

    // prologue: stage tile 0
    STAGE_A(0, 0, 0); STAGE_A(0, 1, 0); STAGE_B(0, 0, 0); STAGE_B(0, 1, 0);
    asm volatile("s_waitcnt vmcnt(0)" ::: "memory");
    __builtin_amdgcn_s_barrier();

#pragma unroll 2
    for (int t = 0; t < 32; ++t) {
        const int cur = t & 1, nxt = cur ^ 1;
        const int ko = (t + 1) * 64;
        bf16x8 bF[4][2];
#pragma unroll
        for (int p = 0; p < 4; ++p) {
            bf16x8 aF[2][2];
            if (p == 0) {
#pragma unroll
                for (int ni = 0; ni < 4; ++ni) {
                    bF[ni][0] = *(const bf16x8*)&sB[cur][(rbB + ni * 16) * 64 + c0];
                    bF[ni][1] = *(const bf16x8*)&sB[cur][(rbB + ni * 16) * 64 + c1];
                }
            }
#pragma unroll
            for (int mil = 0; mil < 2; ++mil) {
                aF[mil][0] = *(const bf16x8*)&sA[cur][(rbA + (2 * p + mil) * 16) * 64 + c0];
                aF[mil][1] = *(const bf16x8*)&sA[cur][(rbA + (2 * p + mil) * 16) * 64 + c1];
            }
            if (t < 31) {
                if (p == 0)      STAGE_A(nxt, 0, ko);
                else if (p == 1) STAGE_A(nxt, 1, ko);
                else if (p == 2) STAGE_B(nxt, 0, ko);
                else             STAGE_B(nxt, 1, ko);
            }
            __builtin_amdgcn_s_barrier();
            asm volatile("s_waitcnt lgkmcnt(0)" ::: "memory");
            __builtin_amdgcn_sched_barrier(0);
            __builtin_amdgcn_s_setprio(1);
#pragma unroll
            for (int mil = 0; mil < 2; ++mil)
#pragma unroll
                for (int ni = 0; ni < 4; ++ni) {
                    acc[2 * p + mil][ni] = mfma16(aF[mil][0], bF[ni][0], acc[2 * p + mil][ni]);
                    acc[2 * p + mil][ni] = mfma16(aF[mil][1], bF[ni][1], acc[2 * p + mil][ni]);
                }
            __builtin_amdgcn_s_setprio(0);
            __builtin_amdgcn_sched_barrier(0);
            if (p < 3) __builtin_amdgcn_s_barrier();
        }
        asm volatile("s_waitcnt vmcnt(0)" ::: "memory");
        __builtin_amdgcn_s_barrier();
    }

    // epilogue: lin = acc[mi][ni<2], gate = acc[mi][ni+2], same j
    const int col16 = l & 15, rg = (l >> 4) * 4;
    const int g2 = ntb * 4 + wc;
#pragma unroll
    for (int ni = 0; ni < 2; ++ni) {
        const int j = g2 * 32 + ni * 16 + col16;
        const float cl = t4[j] + t4[1024 + j];
        const float cg = cG[j];
#pragma unroll
        for (int mi = 0; mi < 8; ++mi) {
            const size_t row0 = m0 + wr * 128 + mi * 16 + rg;
#pragma unroll
            for (int r = 0; r < 4; ++r) {
                float lin = acc[mi][ni][r] + cl;
                float gv = acc[mi][ni + 2][r] + cg;
                float s = 1.0f / (1.0f + __expf(-gv));
                out[(row0 + r) * 1024 + j] = lin * s;
            }
        }
    }
#undef STAGE_A
#undef STAGE_B
}

// ---- logits -----------------------------------------------------------------
__global__ __launch_bounds__(256) void logits_kernel(
    const ushort_t* __restrict__ Abf, const float* __restrict__ Lw,
    const float* __restrict__ cC, float* __restrict__ out) {
    __shared__ float LwS[3][2048];
    int tid = threadIdx.x;
    for (int idx = tid; idx < 6144; idx += 256) {
        int k = idx / 3, t = idx - 3 * k;
        LwS[t][k] = Lw[idx];
    }
    __syncthreads();
    int w = tid >> 6, l = tid & 63;
    float c0 = cC[0], c1 = cC[1], c2 = cC[2];
    for (int r = 0; r < 4; ++r) {
        int row = blockIdx.x * 16 + w * 4 + r;
        const ushort_t* Ar = Abf + (size_t)row * 2048;
        float a0 = 0.f, a1 = 0.f, a2 = 0.f;
#pragma unroll
        for (int i = 0; i < 16; ++i) {
            int k = 2 * l + 128 * i;
            unsigned int x = *(const unsigned int*)(Ar + k);
            float x0 = bf2f(x & 0xffffu), x1 = bf2f(x >> 16);
            float2 w0 = *(const float2*)&LwS[0][k];
            float2 w1 = *(const float2*)&LwS[1][k];
            float2 w2 = *(const float2*)&LwS[2][k];
            a0 += x0 * w0.x + x1 * w0.y;
            a1 += x0 * w1.x + x1 * w1.y;
            a2 += x0 * w2.x + x1 * w2.y;
        }
#pragma unroll
        for (int off = 32; off; off >>= 1) {
            a0 += __shfl_xor(a0, off);
            a1 += __shfl_xor(a1, off);
            a2 += __shfl_xor(a2, off);
        }
        if (l == 0) {
            size_t ob = (size_t)16777216 + (size_t)row * 3;
            out[ob] = a0 + c0;
            out[ob + 1] = a1 + c1;
            out[ob + 2] = a2 + c2;
        }
    }
}

// ---- launch -----------------------------------------------------------------
extern "C" void kernel_launch(void* const* d_in, const int* in_sizes, int n_in,
                              void* d_out, int out_size, void* d_ws, size_t ws_size,
                              hipStream_t stream) {
    const float* dA = (const float*)d_in[0];
    const float* dB = (const float*)d_in[1];
    const float* Wv = (const float*)d_in[6];
    const float* bv = (const float*)d_in[7];
    const float* Wo = (const float*)d_in[8];
    const float* bo = (const float*)d_in[9];
    const float* Wc = (const float*)d_in[10];
    const float* bc = (const float*)d_in[11];
    const float* Wg = (const float*)d_in[12];
    const float* bg = (const float*)d_in[13];
    float* out = (float*)d_out;

    char* ws = (char*)d_ws;
    ushort_t* Abf  = (ushort_t*)(ws);
    ushort_t* WT   = (ushort_t*)(ws + 67108864);
    ushort_t* Wvbf = (ushort_t*)(ws + 75497472);
    ushort_t* WoT  = (ushort_t*)(ws + 83886080);
    ushort_t* WgT  = (ushort_t*)(ws + 92274688);
    ushort_t* Mbuf = (ushort_t*)(ws + 96468992);
    float* t4   = (float*)(ws + 100663296);
    float* cG   = (float*)(ws + 100683776);
    float* cC   = (float*)(ws + 100687872);
    float* Lw   = (float*)(ws + 100688128);

    convA_kernel<<<16384, 256, 0, stream>>>(dA, dB, Abf);
    convC_kernel<<<2048, 256, 0, stream>>>(Wv, Wvbf);
    convT_kernel<<<dim3(32, 32, 4), 256, 0, stream>>>(Wo, WoT, 1024, 1024, 1048576, 1048576);
    convT_kernel<<<dim3(32, 64, 1), 256, 0, stream>>>(Wg, WgT, 2048, 1024, 0, 0);
    hipMemsetAsync(ws + 100663296, 0, 24832, stream);
    biasT2_kernel<<<128, 256, 0, stream>>>(bv, Wo, bo, t4);
    fold_l12<<<dim3(16, 16, 4), 128, 0, stream>>>(Wvbf, WoT, WT, Mbuf);
    fold_l34<<<dim3(16, 16, 2), 128, 0, stream>>>(WgT, Mbuf, WT);
    post_kernel<<<65, 256, 0, stream>>>(t4, Wg, bg, Wc, bc, cG, cC);
    lfold2_kernel<<<512, 256, 0, stream>>>(Mbuf, Wc, Lw);
    main_mm<<<512, 512, 0, stream>>>(Abf, WT, t4, cG, out);
    logits_kernel<<<1024, 256, 0, stream>>>(Abf, Lw, cC, out);
}